// Round 8
// baseline (1567.534 us; speedup 1.0000x reference)
//
#include <hip/hip_runtime.h>

// Dims (fixed by the problem)
#define S_LEN 512
#define BATCH 256
#define EMB_D 300
#define EMB_PAD 320
#define HID 128
#define SB (S_LEN*BATCH)   // 131072 rows (time-major m = s*B + b)
#define CH 128             // time-chunk length
#define NCH 4              // number of chunks
#define GXC_DIR ((size_t)CH*BATCH*512)   // u16 per dir per buffer
#define SMEM_BYTES 86016   // 84 KiB: 2x84 > 160 KiB -> exactly 1 block/CU (role isolation)

typedef __attribute__((ext_vector_type(8))) short bf16x8;   // 8 bf16 = 4 VGPRs
typedef __attribute__((ext_vector_type(4))) float f32x4;
typedef unsigned short u16;
typedef unsigned int   u32;

// ---- bf16 <-> f32 helpers ----
__device__ __forceinline__ float b2f(u16 u) {
    union { u32 i; float f; } v; v.i = ((u32)u) << 16; return v.f;
}
__device__ __forceinline__ u16 f2b(float f) {
    union { float f; u32 i; } v; v.f = f;
    u32 r = v.i + 0x7fffu + ((v.i >> 16) & 1u);   // round-to-nearest-even
    return (u16)(r >> 16);
}
__device__ __forceinline__ float sigf(float x) {
    return __builtin_amdgcn_rcpf(1.f + __expf(-x));
}
__device__ __forceinline__ float tanhf_fast(float x) {
    float e = __expf(2.f * x);
    return 1.f - 2.f * __builtin_amdgcn_rcpf(e + 1.f);
}

// ---- dtype detector: flag=1 if float tensors are bf16, 0 if f32 ----
__global__ void k_detect(const u16* __restrict__ emb_u, int* __restrict__ flag) {
    __shared__ int cnt;
    if (threadIdx.x == 0) cnt = 0;
    __syncthreads();
    float v = b2f(emb_u[2 * threadIdx.x + 64]);
    float a = fabsf(v);
    if (a > 1e-4f && a < 16.f) atomicAdd(&cnt, 1);
    __syncthreads();
    if (threadIdx.x == 0) *flag = (cnt > 128) ? 1 : 0;
}

// ---- weight packing: gate-row permutation row' = 4*j + t (t: 0=i,1=f,2=g,3=o) ----
__global__ void k_packw(const void* __restrict__ src, u16* __restrict__ dst,
                        int Kin, int Kpad, int total, const int* __restrict__ flag) {
    int i = blockIdx.x * 256 + threadIdx.x;
    if (i >= total) return;
    int n = i / Kpad, k = i - n * Kpad;
    int d = n >> 9, r = n & 511, j = r >> 2, t = r & 3;
    size_t si = (size_t)((d << 9) + (t << 7) + j) * Kin + k;
    u16 v = 0;
    if (k < Kin) {
        if (*flag) v = ((const u16*)src)[si];
        else       v = f2b(((const float*)src)[si]);
    }
    dst[i] = v;
}

__global__ void k_packb(const void* __restrict__ src, float* __restrict__ dst,
                        const int* __restrict__ flag) {
    int i = blockIdx.x * 256 + threadIdx.x;
    if (i >= 1024) return;
    int d = i >> 9, r = i & 511, j = r >> 2, t = r & 3;
    size_t si = (d << 9) + (t << 7) + j;
    dst[i] = (*flag) ? b2f(((const u16*)src)[si]) : ((const float*)src)[si];
}

// ---- FUSED kernel: blocks [0,nlstm) = LSTM role (chunk k, r6-proven internals);
// blocks [nlstm, nlstm+1024) = GEMM role (chunk k+1 -> gx_out).
// GEMM role (r8): block = one dir x 64-row A-tile; A staged ONCE into LDS
// (8x less A-traffic + one-time gather/f2b), then 8 n-subtiles: stage B-sub
// (W is L2-hot), MFMA chain, write C. acc = f32x4 (no r4 register blowup).
// Roles are CU-exclusive: 1024 thr + 84 KiB LDS => 1 block/CU; lstm first.
template<int KPAD, bool EMBED, bool IS_L0>
__global__ __launch_bounds__(1024) void k_fused(
    const int* __restrict__ tok, const void* __restrict__ Asrc,
    const u16* __restrict__ W, const float* __restrict__ bias,
    u16* __restrict__ gx_out, const u16* __restrict__ gx_in,
    const u16* __restrict__ Whp,
    u16* __restrict__ h0seq, float* __restrict__ hT,
    u16* __restrict__ hstate, float* __restrict__ cstate,
    int k, int nlstm, int soff0g, int soff1g, const int* __restrict__ flag)
{
    __shared__ __align__(16) char smem[SMEM_BYTES];
    const int tid = threadIdx.x;

    if ((int)blockIdx.x < nlstm) {
        // ================= LSTM role (r6-proven) =================
        u16* hb = (u16*)smem;                    // [2][16][136]
        u16* gb = (u16*)(smem + 8704);           // [2][16][520]
        const int d    = blockIdx.x >> 4;
        const int bg   = blockIdx.x & 15;
        const int wv   = tid >> 6, lane = tid & 63, quad = lane >> 4, col = lane & 15;
        const int soff = (d == 0) ? CH * k : CH * (NCH - 1 - k);

        for (int i = tid; i < 2 * 16 * 136; i += 1024) hb[i] = 0;
        __syncthreads();                          // zero visible before state load
        if (k > 0) {
            for (int i = tid; i < 16 * 128; i += 1024) {
                int bl = i >> 7, j = i & 127;
                hb[bl * 136 + j] = hstate[((size_t)d * BATCH + bg * 16 + bl) * 128 + j];
            }
        }

        // A-frags of W_hh: A[m=lane&15][k=quad*8+j]  [m120-verified]
        const u16* Wd = Whp + (size_t)d * 512 * 128;
        bf16x8 wf[2][4];
#pragma unroll
        for (int mt = 0; mt < 2; ++mt)
#pragma unroll
            for (int ks = 0; ks < 4; ++ks)
                wf[mt][ks] = *(const bf16x8*)(Wd + (size_t)(((wv * 2 + mt) * 16) + col) * 128 + ks * 32 + quad * 8);

        const u16* gxd = gx_in + (size_t)d * GXC_DIR;
        auto sloc = [&](int si) { return (d == 0) ? si : (CH - 1 - si); };
        auto prefetch = [&](int si, int P) {
            const u16* g0 = gxd + ((size_t)sloc(si) * BATCH + bg * 16 + wv) * 512 + lane * 8;
            __builtin_amdgcn_global_load_lds((const __attribute__((address_space(1))) void*)g0,
                (__attribute__((address_space(3))) void*)(gb + (P * 16 + wv) * 520), 16, 0, 0);
        };

        float c[2];
#pragma unroll
        for (int mt = 0; mt < 2; ++mt)
            c[mt] = (k > 0) ? cstate[((size_t)d * BATCH + bg * 16 + col) * 128 + (wv * 2 + mt) * 4 + quad] : 0.f;

        auto step = [&](int si, int P) {
            if (si + 1 < CH) prefetch(si + 1, P ^ 1);
            if constexpr (IS_L0) {
                if (si > 0) {                     // store PREV step's h (published by barrier)
                    int sp = soff + ((d == 0) ? (si - 1) : (CH - si));
                    ushort2 hv = *(const ushort2*)(hb + (P * 16 + wv) * 136 + lane * 2);
                    *(ushort2*)(h0seq + ((size_t)sp * BATCH + bg * 16 + wv) * 256 + (d << 7) + lane * 2) = hv;
                }
            }
            bf16x8 hf[4];
#pragma unroll
            for (int ks = 0; ks < 4; ++ks)
                hf[ks] = *(const bf16x8*)(hb + (P * 16 + col) * 136 + ks * 32 + quad * 8);
            f32x4 z[2];
#pragma unroll
            for (int mt = 0; mt < 2; ++mt) {
                ushort4 gv = *(const ushort4*)(gb + (P * 16 + col) * 520 + (wv * 2 + mt) * 16 + quad * 4);
                z[mt][0] = b2f(gv.x); z[mt][1] = b2f(gv.y); z[mt][2] = b2f(gv.z); z[mt][3] = b2f(gv.w);
            }
#pragma unroll
            for (int ks = 0; ks < 4; ++ks)
#pragma unroll
                for (int mt = 0; mt < 2; ++mt)
                    z[mt] = __builtin_amdgcn_mfma_f32_16x16x32_bf16(wf[mt][ks], hf[ks], z[mt], 0, 0, 0);
#pragma unroll
            for (int mt = 0; mt < 2; ++mt) {
                float iv = sigf(z[mt][0]), fv = sigf(z[mt][1]);
                float gg = tanhf_fast(z[mt][2]), ov = sigf(z[mt][3]);
                c[mt] = fv * c[mt] + iv * gg;
                float hv = ov * tanhf_fast(c[mt]);
                const int j = (wv * 2 + mt) * 4 + quad;
                hb[((P ^ 1) * 16 + col) * 136 + j] = f2b(hv);
                if constexpr (!IS_L0) {
                    if (k == NCH - 1 && si == CH - 1)
                        hT[((size_t)d * BATCH + bg * 16 + col) * 128 + j] = hv;
                }
            }
            __syncthreads();
        };

        prefetch(0, 0);
        __syncthreads();                          // hbuf init + gx(step 0) visible

        for (int si = 0; si < CH; si += 2) {
            step(si, 0);
            step(si + 1, 1);
        }

        if constexpr (IS_L0) {                    // final step's h (in hbuf[0])
            int sp = soff + ((d == 0) ? (CH - 1) : 0);
            ushort2 hv = *(const ushort2*)(hb + wv * 136 + lane * 2);
            *(ushort2*)(h0seq + ((size_t)sp * BATCH + bg * 16 + wv) * 256 + (d << 7) + lane * 2) = hv;
        }
        if (k < NCH - 1) {                        // persist h/c for next chunk
            for (int i = tid; i < 16 * 128; i += 1024) {
                int bl = i >> 7, j = i & 127;
                hstate[((size_t)d * BATCH + bg * 16 + bl) * 128 + j] = hb[bl * 136 + j];
            }
#pragma unroll
            for (int mt = 0; mt < 2; ++mt)
                cstate[((size_t)d * BATCH + bg * 16 + col) * 128 + (wv * 2 + mt) * 4 + quad] = c[mt];
        }
        return;
    }

    // ================= GEMM role: dir x 64-row A-tile, A staged once =================
    const int g = (int)blockIdx.x - nlstm;        // 0..1023
    constexpr int KSTEPS = KPAD / 32;
    constexpr int AST    = KPAD + 8;              // u16 row stride (+16B pad; 2-way banks)
    constexpr int NCHK   = 64 * (KPAD / 8);       // uint4 chunks per 64xKPAD tile
    u16* As = (u16*)smem;                          // [64][AST]
    u16* Bs = (u16*)(smem + (size_t)64 * AST * 2); // [64][AST]
    const int dir  = g >> 9;
    const int m0   = (g & 511) * 64;               // within chunk rows (0..32767)
    const int soff = dir ? soff1g : soff0g;
    const size_t mg0 = (size_t)soff * BATCH;
    const int w = tid >> 6, lane = tid & 63, quad = lane >> 4, l16 = lane & 15;
    const int wm = w >> 2, wn = w & 3;             // 4m x 4n waves, 16x16 frag each
    const bool is_bf = EMBED ? (*flag != 0) : true;

    // ---- stage A once: 64 rows x KPAD (gather + f2b happen ONCE, not 8x) ----
    for (int ch = tid; ch < NCHK; ch += 1024) {
        int row = ch / (KPAD / 8), seg = ch % (KPAD / 8);
        uint4 v;
        if constexpr (EMBED) {
            u32 u[4];
            size_t m = mg0 + m0 + row;
            int s = (int)(m >> 8), b = (int)(m & 255);
            size_t aro = (size_t)tok[b * S_LEN + s] * EMB_D;
            if (is_bf) {
                const u16* ar = (const u16*)Asrc + aro;
#pragma unroll
                for (int i = 0; i < 4; ++i) {
                    int cc = seg * 8 + 2 * i;              // even -> 4B aligned pair
                    u[i] = (cc < EMB_D) ? *(const u32*)(ar + cc) : 0u;
                }
            } else {
                const float* ar = (const float*)Asrc + aro;
#pragma unroll
                for (int i = 0; i < 4; ++i) {
                    int cc = seg * 8 + 2 * i;
                    if (cc < EMB_D) {
                        float2 f = *(const float2*)(ar + cc);
                        u[i] = (u32)f2b(f.x) | ((u32)f2b(f.y) << 16);
                    } else u[i] = 0u;
                }
            }
            v.x = u[0]; v.y = u[1]; v.z = u[2]; v.w = u[3];
        } else {
            v = *(const uint4*)((const u16*)Asrc + (mg0 + m0 + row) * KPAD + seg * 8);
        }
        *(uint4*)(As + (size_t)row * AST + seg * 8) = v;
    }

    // ---- 8 n-subtiles of 64 gate-cols ----
    for (int j = 0; j < 8; ++j) {
        __syncthreads();                           // prev compute done before Bs overwrite
        for (int ch = tid; ch < NCHK; ch += 1024) {
            int row = ch / (KPAD / 8), seg = ch % (KPAD / 8);
            uint4 v = *(const uint4*)(W + (size_t)(dir * 512 + j * 64 + row) * KPAD + seg * 8);
            *(uint4*)(Bs + (size_t)row * AST + seg * 8) = v;
        }
        __syncthreads();                           // A (j==0) + B(j) visible
        f32x4 acc = {};
#pragma unroll
        for (int kk = 0; kk < KSTEPS; ++kk) {
            bf16x8 af = *(const bf16x8*)(As + (size_t)(wm * 16 + l16) * AST + kk * 32 + quad * 8);
            bf16x8 bf = *(const bf16x8*)(Bs + (size_t)(wn * 16 + l16) * AST + kk * 32 + quad * 8);
            acc = __builtin_amdgcn_mfma_f32_16x16x32_bf16(af, bf, acc, 0, 0, 0);
        }
        // C/D layout: col = lane&15, row = quad*4 + reg  [m89-verified]
#pragma unroll
        for (int r = 0; r < 4; ++r) {
            int mloc = m0 + wm * 16 + quad * 4 + r;
            int nloc = j * 64 + wn * 16 + l16;
            float vv = acc[r] + bias[dir * 512 + nloc];
            gx_out[(size_t)dir * GXC_DIR + (size_t)mloc * 512 + nloc] = f2b(vv);
        }
    }
}

// ---- FC head (dtype-flagged weights and output) ----
__global__ void k_fc(const float* __restrict__ hT,
                     const void* __restrict__ fc1w, const void* __restrict__ fc1b,
                     const void* __restrict__ fc2w, const void* __restrict__ fc2b,
                     void* __restrict__ out, const int* __restrict__ flag) {
    int b = blockIdx.x, j = threadIdx.x;
    bool is_bf = (*flag != 0);
    __shared__ float u[128];
    float a = is_bf ? b2f(((const u16*)fc1b)[j]) : ((const float*)fc1b)[j];
    for (int k = 0; k < 256; ++k) {
        float x = hT[((size_t)(k >> 7) * BATCH + b) * 128 + (k & 127)];
        float w = is_bf ? b2f(((const u16*)fc1w)[j * 256 + k]) : ((const float*)fc1w)[j * 256 + k];
        a += x * w;
    }
    u[j] = fmaxf(a, 0.f);
    __syncthreads();
    if (j < 2) {
        float a2 = is_bf ? b2f(((const u16*)fc2b)[j]) : ((const float*)fc2b)[j];
        for (int q = 0; q < 128; ++q) {
            float w = is_bf ? b2f(((const u16*)fc2w)[j * 128 + q]) : ((const float*)fc2w)[j * 128 + q];
            a2 += u[q] * w;
        }
        if (is_bf) ((u16*)out)[b * 2 + j] = f2b(a2);
        else       ((float*)out)[b * 2 + j] = a2;
    }
}

extern "C" void kernel_launch(void* const* d_in, const int* in_sizes, int n_in,
                              void* d_out, int out_size, void* d_ws, size_t ws_size,
                              hipStream_t stream) {
    const int*  tok   = (const int*)d_in[0];
    const void* emb   = d_in[1];
    const void* w_ih0 = d_in[2];
    const void* w_hh0 = d_in[3];
    const void* b0    = d_in[4];
    const void* w_ih1 = d_in[5];
    const void* w_hh1 = d_in[6];
    const void* b1    = d_in[7];
    const void* fc1w  = d_in[8];
    const void* fc1b  = d_in[9];
    const void* fc2w  = d_in[10];
    const void* fc2b  = d_in[11];

    char* ws = (char*)d_ws;
    size_t off = 0;
    auto alloc = [&](size_t bytes) -> void* {
        void* p = ws + off; off += (bytes + 255) & ~(size_t)255; return p;
    };
    int*   flag   = (int*)alloc(256);
    u16*   Wp0    = (u16*)alloc(1024 * 320 * 2);
    u16*   Wp1    = (u16*)alloc(1024 * 256 * 2);
    u16*   Whp0   = (u16*)alloc(1024 * 128 * 2);
    u16*   Whp1   = (u16*)alloc(1024 * 128 * 2);
    float* bp0    = (float*)alloc(1024 * 4);
    float* bp1    = (float*)alloc(1024 * 4);
    float* hT     = (float*)alloc((size_t)2 * BATCH * 128 * 4);
    u16*   hstate = (u16*)alloc((size_t)2 * BATCH * 128 * 2);
    float* cstate = (float*)alloc((size_t)2 * BATCH * 128 * 4);
    u16*   h0seq  = (u16*)alloc((size_t)SB * 256 * 2);           // 64 MiB
    size_t bufb   = 2 * GXC_DIR * sizeof(u16);                   // 64 MiB (both dirs)
    u16*   gxcA   = (u16*)alloc(bufb);
    bool overlap  = ws_size >= off + bufb;                       // room for 2nd buffer?
    u16*   gxcB   = overlap ? (u16*)alloc(bufb) : gxcA;

    k_detect<<<1, 256, 0, stream>>>((const u16*)emb, flag);

    k_packw<<<(1024 * 320 + 255) / 256, 256, 0, stream>>>(w_ih0, Wp0, 300, 320, 1024 * 320, flag);
    k_packw<<<(1024 * 256 + 255) / 256, 256, 0, stream>>>(w_ih1, Wp1, 256, 256, 1024 * 256, flag);
    k_packw<<<(1024 * 128 + 255) / 256, 256, 0, stream>>>(w_hh0, Whp0, 128, 128, 1024 * 128, flag);
    k_packw<<<(1024 * 128 + 255) / 256, 256, 0, stream>>>(w_hh1, Whp1, 128, 128, 1024 * 128, flag);
    k_packb<<<4, 256, 0, stream>>>(b0, bp0, flag);
    k_packb<<<4, 256, 0, stream>>>(b1, bp1, flag);

    const int NG = 1024;   // gemm blocks per chunk: 2 dirs x 512 m-tiles

    if (overlap) {
        // ---- L0: gemm chunk0 standalone, then lstm(k) || gemm(k+1) ----
        k_fused<320, true, true><<<NG, 1024, 0, stream>>>(
            tok, emb, Wp0, bp0, gxcA, gxcA, Whp0, h0seq, nullptr, hstate, cstate,
            0, 0, 0, CH * (NCH - 1), flag);
        for (int k = 0; k < NCH; ++k) {
            int ng = (k < NCH - 1) ? NG : 0;
            u16* gin  = (k & 1) ? gxcB : gxcA;
            u16* gout = (k & 1) ? gxcA : gxcB;
            k_fused<320, true, true><<<32 + ng, 1024, 0, stream>>>(
                tok, emb, Wp0, bp0, gout, gin, Whp0, h0seq, nullptr, hstate, cstate,
                k, 32, CH * (k + 1), CH * (NCH - 2 - k), flag);
        }
        // ---- L1 ----
        k_fused<256, false, false><<<NG, 1024, 0, stream>>>(
            nullptr, h0seq, Wp1, bp1, gxcA, gxcA, Whp1, nullptr, hT, hstate, cstate,
            0, 0, 0, CH * (NCH - 1), flag);
        for (int k = 0; k < NCH; ++k) {
            int ng = (k < NCH - 1) ? NG : 0;
            u16* gin  = (k & 1) ? gxcB : gxcA;
            u16* gout = (k & 1) ? gxcA : gxcB;
            k_fused<256, false, false><<<32 + ng, 1024, 0, stream>>>(
                nullptr, h0seq, Wp1, bp1, gout, gin, Whp1, nullptr, hT, hstate, cstate,
                k, 32, CH * (k + 1), CH * (NCH - 2 - k), flag);
        }
    } else {
        // ---- serial fallback (r6 schedule), single gxc buffer ----
        for (int k = 0; k < NCH; ++k) {
            k_fused<320, true, true><<<NG, 1024, 0, stream>>>(
                tok, emb, Wp0, bp0, gxcA, gxcA, Whp0, h0seq, nullptr, hstate, cstate,
                0, 0, CH * k, CH * (NCH - 1 - k), flag);
            k_fused<320, true, true><<<32, 1024, 0, stream>>>(
                tok, emb, Wp0, bp0, gxcA, gxcA, Whp0, h0seq, nullptr, hstate, cstate,
                k, 32, 0, 0, flag);
        }
        for (int k = 0; k < NCH; ++k) {
            k_fused<256, false, false><<<NG, 1024, 0, stream>>>(
                nullptr, h0seq, Wp1, bp1, gxcA, gxcA, Whp1, nullptr, hT, hstate, cstate,
                0, 0, CH * k, CH * (NCH - 1 - k), flag);
            k_fused<256, false, false><<<32, 1024, 0, stream>>>(
                nullptr, h0seq, Wp1, bp1, gxcA, gxcA, Whp1, nullptr, hT, hstate, cstate,
                k, 32, 0, 0, flag);
        }
    }
    k_fc<<<256, 128, 0, stream>>>(hT, fc1w, fc1b, fc2w, fc2b, d_out, flag);
}

// Round 9
// 1526.941 us; speedup vs baseline: 1.0266x; 1.0266x over previous
//
#include <hip/hip_runtime.h>

// Dims (fixed by the problem)
#define S_LEN 512
#define BATCH 256
#define EMB_D 300
#define EMB_PAD 320
#define HID 128
#define SB (S_LEN*BATCH)   // 131072 rows (time-major m = s*B + b)
#define CH 128             // time-chunk length
#define NCH 4              // number of chunks
#define GXC_DIR ((size_t)CH*BATCH*512)   // u16 per dir per buffer
#define SMEM_BYTES 125952  // 123 KiB: A + 2xB tiles; >80K -> 1 block/CU (role isolation)

typedef __attribute__((ext_vector_type(8))) short bf16x8;   // 8 bf16 = 4 VGPRs
typedef __attribute__((ext_vector_type(4))) float f32x4;
typedef unsigned short u16;
typedef unsigned int   u32;

// ---- bf16 <-> f32 helpers ----
__device__ __forceinline__ float b2f(u16 u) {
    union { u32 i; float f; } v; v.i = ((u32)u) << 16; return v.f;
}
__device__ __forceinline__ u16 f2b(float f) {
    union { float f; u32 i; } v; v.f = f;
    u32 r = v.i + 0x7fffu + ((v.i >> 16) & 1u);   // round-to-nearest-even
    return (u16)(r >> 16);
}
__device__ __forceinline__ float sigf(float x) {
    return __builtin_amdgcn_rcpf(1.f + __expf(-x));
}
__device__ __forceinline__ float tanhf_fast(float x) {
    float e = __expf(2.f * x);
    return 1.f - 2.f * __builtin_amdgcn_rcpf(e + 1.f);
}

// ---- dtype detector: flag=1 if float tensors are bf16, 0 if f32 ----
__global__ void k_detect(const u16* __restrict__ emb_u, int* __restrict__ flag) {
    __shared__ int cnt;
    if (threadIdx.x == 0) cnt = 0;
    __syncthreads();
    float v = b2f(emb_u[2 * threadIdx.x + 64]);
    float a = fabsf(v);
    if (a > 1e-4f && a < 16.f) atomicAdd(&cnt, 1);
    __syncthreads();
    if (threadIdx.x == 0) *flag = (cnt > 128) ? 1 : 0;
}

// ---- weight packing: gate-row permutation row' = 4*j + t (t: 0=i,1=f,2=g,3=o) ----
__global__ void k_packw(const void* __restrict__ src, u16* __restrict__ dst,
                        int Kin, int Kpad, int total, const int* __restrict__ flag) {
    int i = blockIdx.x * 256 + threadIdx.x;
    if (i >= total) return;
    int n = i / Kpad, k = i - n * Kpad;
    int d = n >> 9, r = n & 511, j = r >> 2, t = r & 3;
    size_t si = (size_t)((d << 9) + (t << 7) + j) * Kin + k;
    u16 v = 0;
    if (k < Kin) {
        if (*flag) v = ((const u16*)src)[si];
        else       v = f2b(((const float*)src)[si]);
    }
    dst[i] = v;
}

__global__ void k_packb(const void* __restrict__ src, float* __restrict__ dst,
                        const int* __restrict__ flag) {
    int i = blockIdx.x * 256 + threadIdx.x;
    if (i >= 1024) return;
    int d = i >> 9, r = i & 511, j = r >> 2, t = r & 3;
    size_t si = (d << 9) + (t << 7) + j;
    dst[i] = (*flag) ? b2f(((const u16*)src)[si]) : ((const float*)src)[si];
}

// ---- FUSED kernel: blocks [0,nlstm) = LSTM role (chunk k, r6-proven internals);
// blocks [nlstm, nlstm+1024) = GEMM role (chunk k+1 -> gx_out).
// GEMM role (r9): A staged once + A-frags cached in VGPRs (LDS read 1x, not 8x);
// B double-buffered, issue-early/write-late staging (T14), 1 barrier/subtile
// (was 2); 16 -> 9 barriers per block. Roles CU-exclusive (123K LDS, 1 blk/CU).
template<int KPAD, bool EMBED, bool IS_L0>
__global__ __launch_bounds__(1024) void k_fused(
    const int* __restrict__ tok, const void* __restrict__ Asrc,
    const u16* __restrict__ W, const float* __restrict__ bias,
    u16* __restrict__ gx_out, const u16* __restrict__ gx_in,
    const u16* __restrict__ Whp,
    u16* __restrict__ h0seq, float* __restrict__ hT,
    u16* __restrict__ hstate, float* __restrict__ cstate,
    int k, int nlstm, int soff0g, int soff1g, const int* __restrict__ flag)
{
    __shared__ __align__(16) char smem[SMEM_BYTES];
    const int tid = threadIdx.x;

    if ((int)blockIdx.x < nlstm) {
        // ================= LSTM role (r6-proven) =================
        u16* hb = (u16*)smem;                    // [2][16][136]
        u16* gb = (u16*)(smem + 8704);           // [2][16][520]
        const int d    = blockIdx.x >> 4;
        const int bg   = blockIdx.x & 15;
        const int wv   = tid >> 6, lane = tid & 63, quad = lane >> 4, col = lane & 15;
        const int soff = (d == 0) ? CH * k : CH * (NCH - 1 - k);

        for (int i = tid; i < 2 * 16 * 136; i += 1024) hb[i] = 0;
        __syncthreads();                          // zero visible before state load
        if (k > 0) {
            for (int i = tid; i < 16 * 128; i += 1024) {
                int bl = i >> 7, j = i & 127;
                hb[bl * 136 + j] = hstate[((size_t)d * BATCH + bg * 16 + bl) * 128 + j];
            }
        }

        // A-frags of W_hh: A[m=lane&15][k=quad*8+j]  [m120-verified]
        const u16* Wd = Whp + (size_t)d * 512 * 128;
        bf16x8 wf[2][4];
#pragma unroll
        for (int mt = 0; mt < 2; ++mt)
#pragma unroll
            for (int ks = 0; ks < 4; ++ks)
                wf[mt][ks] = *(const bf16x8*)(Wd + (size_t)(((wv * 2 + mt) * 16) + col) * 128 + ks * 32 + quad * 8);

        const u16* gxd = gx_in + (size_t)d * GXC_DIR;
        auto sloc = [&](int si) { return (d == 0) ? si : (CH - 1 - si); };
        auto prefetch = [&](int si, int P) {
            const u16* g0 = gxd + ((size_t)sloc(si) * BATCH + bg * 16 + wv) * 512 + lane * 8;
            __builtin_amdgcn_global_load_lds((const __attribute__((address_space(1))) void*)g0,
                (__attribute__((address_space(3))) void*)(gb + (P * 16 + wv) * 520), 16, 0, 0);
        };

        float c[2];
#pragma unroll
        for (int mt = 0; mt < 2; ++mt)
            c[mt] = (k > 0) ? cstate[((size_t)d * BATCH + bg * 16 + col) * 128 + (wv * 2 + mt) * 4 + quad] : 0.f;

        auto step = [&](int si, int P) {
            if (si + 1 < CH) prefetch(si + 1, P ^ 1);
            if constexpr (IS_L0) {
                if (si > 0) {                     // store PREV step's h (published by barrier)
                    int sp = soff + ((d == 0) ? (si - 1) : (CH - si));
                    ushort2 hv = *(const ushort2*)(hb + (P * 16 + wv) * 136 + lane * 2);
                    *(ushort2*)(h0seq + ((size_t)sp * BATCH + bg * 16 + wv) * 256 + (d << 7) + lane * 2) = hv;
                }
            }
            bf16x8 hf[4];
#pragma unroll
            for (int ks = 0; ks < 4; ++ks)
                hf[ks] = *(const bf16x8*)(hb + (P * 16 + col) * 136 + ks * 32 + quad * 8);
            f32x4 z[2];
#pragma unroll
            for (int mt = 0; mt < 2; ++mt) {
                ushort4 gv = *(const ushort4*)(gb + (P * 16 + col) * 520 + (wv * 2 + mt) * 16 + quad * 4);
                z[mt][0] = b2f(gv.x); z[mt][1] = b2f(gv.y); z[mt][2] = b2f(gv.z); z[mt][3] = b2f(gv.w);
            }
#pragma unroll
            for (int ks = 0; ks < 4; ++ks)
#pragma unroll
                for (int mt = 0; mt < 2; ++mt)
                    z[mt] = __builtin_amdgcn_mfma_f32_16x16x32_bf16(wf[mt][ks], hf[ks], z[mt], 0, 0, 0);
#pragma unroll
            for (int mt = 0; mt < 2; ++mt) {
                float iv = sigf(z[mt][0]), fv = sigf(z[mt][1]);
                float gg = tanhf_fast(z[mt][2]), ov = sigf(z[mt][3]);
                c[mt] = fv * c[mt] + iv * gg;
                float hv = ov * tanhf_fast(c[mt]);
                const int j = (wv * 2 + mt) * 4 + quad;
                hb[((P ^ 1) * 16 + col) * 136 + j] = f2b(hv);
                if constexpr (!IS_L0) {
                    if (k == NCH - 1 && si == CH - 1)
                        hT[((size_t)d * BATCH + bg * 16 + col) * 128 + j] = hv;
                }
            }
            __syncthreads();
        };

        prefetch(0, 0);
        __syncthreads();                          // hbuf init + gx(step 0) visible

        for (int si = 0; si < CH; si += 2) {
            step(si, 0);
            step(si + 1, 1);
        }

        if constexpr (IS_L0) {                    // final step's h (in hbuf[0])
            int sp = soff + ((d == 0) ? (CH - 1) : 0);
            ushort2 hv = *(const ushort2*)(hb + wv * 136 + lane * 2);
            *(ushort2*)(h0seq + ((size_t)sp * BATCH + bg * 16 + wv) * 256 + (d << 7) + lane * 2) = hv;
        }
        if (k < NCH - 1) {                        // persist h/c for next chunk
            for (int i = tid; i < 16 * 128; i += 1024) {
                int bl = i >> 7, j = i & 127;
                hstate[((size_t)d * BATCH + bg * 16 + bl) * 128 + j] = hb[bl * 136 + j];
            }
#pragma unroll
            for (int mt = 0; mt < 2; ++mt)
                cstate[((size_t)d * BATCH + bg * 16 + col) * 128 + (wv * 2 + mt) * 4 + quad] = c[mt];
        }
        return;
    }

    // ========== GEMM role: dir x 64-row A-tile; A-frags in VGPR, B dbuf ==========
    const int g = (int)blockIdx.x - nlstm;        // 0..1023
    constexpr int KSTEPS = KPAD / 32;
    constexpr int AST    = KPAD + 8;              // u16 row stride (16B-aligned rows)
    constexpr int CPR    = KPAD / 8;              // uint4 chunks per row
    constexpr int NCHK   = 64 * CPR;              // uint4 chunks per 64xKPAD tile
    u16* As  = (u16*)smem;                         // [64][AST]
    u16* Bs0 = (u16*)(smem + (size_t)64 * AST * 2);
    u16* Bs1 = Bs0 + (size_t)64 * AST;
    const int dir  = g >> 9;
    const int m0   = (g & 511) * 64;               // within chunk rows (0..32767)
    const int soff = dir ? soff1g : soff0g;
    const size_t mg0 = (size_t)soff * BATCH;
    const int w = tid >> 6, lane = tid & 63, quad = lane >> 4, l16 = lane & 15;
    const int wm = w >> 2, wn = w & 3;             // 4m x 4n waves, 16x16 frag each
    const bool is_bf = EMBED ? (*flag != 0) : true;
    const u16* Wdir = W + (size_t)dir * 512 * KPAD;

    // ---- stage A once (gather + f2b happen ONCE) ----
    for (int ch = tid; ch < NCHK; ch += 1024) {
        int row = ch / CPR, seg = ch % CPR;
        uint4 v;
        if constexpr (EMBED) {
            u32 u[4];
            size_t m = mg0 + m0 + row;
            int s = (int)(m >> 8), b = (int)(m & 255);
            size_t aro = (size_t)tok[b * S_LEN + s] * EMB_D;
            if (is_bf) {
                const u16* ar = (const u16*)Asrc + aro;
#pragma unroll
                for (int i = 0; i < 4; ++i) {
                    int cc = seg * 8 + 2 * i;              // even -> 4B aligned pair
                    u[i] = (cc < EMB_D) ? *(const u32*)(ar + cc) : 0u;
                }
            } else {
                const float* ar = (const float*)Asrc + aro;
#pragma unroll
                for (int i = 0; i < 4; ++i) {
                    int cc = seg * 8 + 2 * i;
                    if (cc < EMB_D) {
                        float2 f = *(const float2*)(ar + cc);
                        u[i] = (u32)f2b(f.x) | ((u32)f2b(f.y) << 16);
                    } else u[i] = 0u;
                }
            }
            v.x = u[0]; v.y = u[1]; v.z = u[2]; v.w = u[3];
        } else {
            v = *(const uint4*)((const u16*)Asrc + (mg0 + m0 + row) * KPAD + seg * 8);
        }
        *(uint4*)(As + (size_t)row * AST + seg * 8) = v;
    }
    // ---- stage B(0) -> Bs0 ----
    for (int ch = tid; ch < NCHK; ch += 1024) {
        int row = ch / CPR, seg = ch % CPR;
        uint4 v = *(const uint4*)(Wdir + (size_t)row * KPAD + seg * 8);
        *(uint4*)(Bs0 + (size_t)row * AST + seg * 8) = v;
    }
    __syncthreads();                               // A + B0 visible

    // ---- cache A-frags in VGPRs (LDS read once, not 8x) ----
    bf16x8 afr[KSTEPS];
#pragma unroll
    for (int kk = 0; kk < KSTEPS; ++kk)
        afr[kk] = *(const bf16x8*)(As + (size_t)(wm * 16 + l16) * AST + kk * 32 + quad * 8);

    // ---- 8 n-subtiles: issue B(j+1) loads early, MFMA, write B(j+1), barrier ----
    for (int j = 0; j < 8; ++j) {
        uint4 v0, v1, v2;
        const bool more = (j + 1 < 8);
        if (more) {                                // issue-early (T14): L2-hot W loads
            const u16* Wj = Wdir + (size_t)(j + 1) * 64 * KPAD;
            { int row = tid / CPR, seg = tid % CPR;
              v0 = *(const uint4*)(Wj + (size_t)row * KPAD + seg * 8); }
            { int ch = tid + 1024; int row = ch / CPR, seg = ch % CPR;
              v1 = *(const uint4*)(Wj + (size_t)row * KPAD + seg * 8); }
            if (tid + 2048 < NCHK) { int ch = tid + 2048; int row = ch / CPR, seg = ch % CPR;
              v2 = *(const uint4*)(Wj + (size_t)row * KPAD + seg * 8); }
        }
        const u16* Bc = (j & 1) ? Bs1 : Bs0;
        f32x4 acc = {};
#pragma unroll
        for (int kk = 0; kk < KSTEPS; ++kk) {
            bf16x8 bf = *(const bf16x8*)(Bc + (size_t)(wn * 16 + l16) * AST + kk * 32 + quad * 8);
            acc = __builtin_amdgcn_mfma_f32_16x16x32_bf16(afr[kk], bf, acc, 0, 0, 0);
        }
        if (more) {                                // write-late into the other buffer
            u16* Bn = (j & 1) ? Bs0 : Bs1;
            { int row = tid / CPR, seg = tid % CPR;
              *(uint4*)(Bn + (size_t)row * AST + seg * 8) = v0; }
            { int ch = tid + 1024; int row = ch / CPR, seg = ch % CPR;
              *(uint4*)(Bn + (size_t)row * AST + seg * 8) = v1; }
            if (tid + 2048 < NCHK) { int ch = tid + 2048; int row = ch / CPR, seg = ch % CPR;
              *(uint4*)(Bn + (size_t)row * AST + seg * 8) = v2; }
        }
        __syncthreads();                           // publish B(j+1); guard dbuf reuse
        // C/D layout: col = lane&15, row = quad*4 + reg  [m89-verified]
#pragma unroll
        for (int r = 0; r < 4; ++r) {
            int mloc = m0 + wm * 16 + quad * 4 + r;
            int nloc = j * 64 + wn * 16 + l16;
            float vv = acc[r] + bias[dir * 512 + nloc];
            gx_out[(size_t)dir * GXC_DIR + (size_t)mloc * 512 + nloc] = f2b(vv);
        }
    }
}

// ---- FC head (dtype-flagged weights and output) ----
__global__ void k_fc(const float* __restrict__ hT,
                     const void* __restrict__ fc1w, const void* __restrict__ fc1b,
                     const void* __restrict__ fc2w, const void* __restrict__ fc2b,
                     void* __restrict__ out, const int* __restrict__ flag) {
    int b = blockIdx.x, j = threadIdx.x;
    bool is_bf = (*flag != 0);
    __shared__ float u[128];
    float a = is_bf ? b2f(((const u16*)fc1b)[j]) : ((const float*)fc1b)[j];
    for (int k = 0; k < 256; ++k) {
        float x = hT[((size_t)(k >> 7) * BATCH + b) * 128 + (k & 127)];
        float w = is_bf ? b2f(((const u16*)fc1w)[j * 256 + k]) : ((const float*)fc1w)[j * 256 + k];
        a += x * w;
    }
    u[j] = fmaxf(a, 0.f);
    __syncthreads();
    if (j < 2) {
        float a2 = is_bf ? b2f(((const u16*)fc2b)[j]) : ((const float*)fc2b)[j];
        for (int q = 0; q < 128; ++q) {
            float w = is_bf ? b2f(((const u16*)fc2w)[j * 128 + q]) : ((const float*)fc2w)[j * 128 + q];
            a2 += u[q] * w;
        }
        if (is_bf) ((u16*)out)[b * 2 + j] = f2b(a2);
        else       ((float*)out)[b * 2 + j] = a2;
    }
}

extern "C" void kernel_launch(void* const* d_in, const int* in_sizes, int n_in,
                              void* d_out, int out_size, void* d_ws, size_t ws_size,
                              hipStream_t stream) {
    const int*  tok   = (const int*)d_in[0];
    const void* emb   = d_in[1];
    const void* w_ih0 = d_in[2];
    const void* w_hh0 = d_in[3];
    const void* b0    = d_in[4];
    const void* w_ih1 = d_in[5];
    const void* w_hh1 = d_in[6];
    const void* b1    = d_in[7];
    const void* fc1w  = d_in[8];
    const void* fc1b  = d_in[9];
    const void* fc2w  = d_in[10];
    const void* fc2b  = d_in[11];

    char* ws = (char*)d_ws;
    size_t off = 0;
    auto alloc = [&](size_t bytes) -> void* {
        void* p = ws + off; off += (bytes + 255) & ~(size_t)255; return p;
    };
    int*   flag   = (int*)alloc(256);
    u16*   Wp0    = (u16*)alloc(1024 * 320 * 2);
    u16*   Wp1    = (u16*)alloc(1024 * 256 * 2);
    u16*   Whp0   = (u16*)alloc(1024 * 128 * 2);
    u16*   Whp1   = (u16*)alloc(1024 * 128 * 2);
    float* bp0    = (float*)alloc(1024 * 4);
    float* bp1    = (float*)alloc(1024 * 4);
    float* hT     = (float*)alloc((size_t)2 * BATCH * 128 * 4);
    u16*   hstate = (u16*)alloc((size_t)2 * BATCH * 128 * 2);
    float* cstate = (float*)alloc((size_t)2 * BATCH * 128 * 4);
    u16*   h0seq  = (u16*)alloc((size_t)SB * 256 * 2);           // 64 MiB
    size_t bufb   = 2 * GXC_DIR * sizeof(u16);                   // 64 MiB (both dirs)
    u16*   gxcA   = (u16*)alloc(bufb);
    bool overlap  = ws_size >= off + bufb;                       // room for 2nd buffer?
    u16*   gxcB   = overlap ? (u16*)alloc(bufb) : gxcA;

    k_detect<<<1, 256, 0, stream>>>((const u16*)emb, flag);

    k_packw<<<(1024 * 320 + 255) / 256, 256, 0, stream>>>(w_ih0, Wp0, 300, 320, 1024 * 320, flag);
    k_packw<<<(1024 * 256 + 255) / 256, 256, 0, stream>>>(w_ih1, Wp1, 256, 256, 1024 * 256, flag);
    k_packw<<<(1024 * 128 + 255) / 256, 256, 0, stream>>>(w_hh0, Whp0, 128, 128, 1024 * 128, flag);
    k_packw<<<(1024 * 128 + 255) / 256, 256, 0, stream>>>(w_hh1, Whp1, 128, 128, 1024 * 128, flag);
    k_packb<<<4, 256, 0, stream>>>(b0, bp0, flag);
    k_packb<<<4, 256, 0, stream>>>(b1, bp1, flag);

    const int NG = 1024;   // gemm blocks per chunk: 2 dirs x 512 m-tiles

    if (overlap) {
        // ---- L0: gemm chunk0 standalone, then lstm(k) || gemm(k+1) ----
        k_fused<320, true, true><<<NG, 1024, 0, stream>>>(
            tok, emb, Wp0, bp0, gxcA, gxcA, Whp0, h0seq, nullptr, hstate, cstate,
            0, 0, 0, CH * (NCH - 1), flag);
        for (int k = 0; k < NCH; ++k) {
            int ng = (k < NCH - 1) ? NG : 0;
            u16* gin  = (k & 1) ? gxcB : gxcA;
            u16* gout = (k & 1) ? gxcA : gxcB;
            k_fused<320, true, true><<<32 + ng, 1024, 0, stream>>>(
                tok, emb, Wp0, bp0, gout, gin, Whp0, h0seq, nullptr, hstate, cstate,
                k, 32, CH * (k + 1), CH * (NCH - 2 - k), flag);
        }
        // ---- L1 ----
        k_fused<256, false, false><<<NG, 1024, 0, stream>>>(
            nullptr, h0seq, Wp1, bp1, gxcA, gxcA, Whp1, nullptr, hT, hstate, cstate,
            0, 0, 0, CH * (NCH - 1), flag);
        for (int k = 0; k < NCH; ++k) {
            int ng = (k < NCH - 1) ? NG : 0;
            u16* gin  = (k & 1) ? gxcB : gxcA;
            u16* gout = (k & 1) ? gxcA : gxcB;
            k_fused<256, false, false><<<32 + ng, 1024, 0, stream>>>(
                nullptr, h0seq, Wp1, bp1, gout, gin, Whp1, nullptr, hT, hstate, cstate,
                k, 32, CH * (k + 1), CH * (NCH - 2 - k), flag);
        }
    } else {
        // ---- serial fallback (r6 schedule), single gxc buffer ----
        for (int k = 0; k < NCH; ++k) {
            k_fused<320, true, true><<<NG, 1024, 0, stream>>>(
                tok, emb, Wp0, bp0, gxcA, gxcA, Whp0, h0seq, nullptr, hstate, cstate,
                0, 0, CH * k, CH * (NCH - 1 - k), flag);
            k_fused<320, true, true><<<32, 1024, 0, stream>>>(
                tok, emb, Wp0, bp0, gxcA, gxcA, Whp0, h0seq, nullptr, hstate, cstate,
                k, 32, 0, 0, flag);
        }
        for (int k = 0; k < NCH; ++k) {
            k_fused<256, false, false><<<NG, 1024, 0, stream>>>(
                nullptr, h0seq, Wp1, bp1, gxcA, gxcA, Whp1, nullptr, hT, hstate, cstate,
                0, 0, CH * k, CH * (NCH - 1 - k), flag);
            k_fused<256, false, false><<<32, 1024, 0, stream>>>(
                nullptr, h0seq, Wp1, bp1, gxcA, gxcA, Whp1, nullptr, hT, hstate, cstate,
                k, 32, 0, 0, flag);
        }
    }
    k_fc<<<256, 128, 0, stream>>>(hT, fc1w, fc1b, fc2w, fc2b, d_out, flag);
}

// Round 10
// 1512.652 us; speedup vs baseline: 1.0363x; 1.0094x over previous
//
#include <hip/hip_runtime.h>

// Dims (fixed by the problem)
#define S_LEN 512
#define BATCH 256
#define EMB_D 300
#define EMB_PAD 320
#define HID 128
#define SB (S_LEN*BATCH)   // 131072 rows (time-major m = s*B + b)
#define CH 128             // time-chunk length
#define NCH 4              // number of chunks
#define GXC_DIR ((size_t)CH*BATCH*512)   // u16 per dir per buffer
#define SMEM_BYTES 125952  // 123 KiB: gemm A + 2xB tiles; >80K -> 1 block/CU (role isolation)

typedef __attribute__((ext_vector_type(8))) short bf16x8;   // 8 bf16 = 4 VGPRs
typedef __attribute__((ext_vector_type(4))) float f32x4;
typedef unsigned short u16;
typedef unsigned int   u32;

// ---- bf16 <-> f32 helpers ----
__device__ __forceinline__ float b2f(u16 u) {
    union { u32 i; float f; } v; v.i = ((u32)u) << 16; return v.f;
}
__device__ __forceinline__ u16 f2b(float f) {
    union { float f; u32 i; } v; v.f = f;
    u32 r = v.i + 0x7fffu + ((v.i >> 16) & 1u);   // round-to-nearest-even
    return (u16)(r >> 16);
}
__device__ __forceinline__ float sigf(float x) {
    return __builtin_amdgcn_rcpf(1.f + __expf(-x));
}
__device__ __forceinline__ float tanhf_fast(float x) {
    float e = __expf(2.f * x);
    return 1.f - 2.f * __builtin_amdgcn_rcpf(e + 1.f);
}

// ---- dtype detector: flag=1 if float tensors are bf16, 0 if f32 ----
__global__ void k_detect(const u16* __restrict__ emb_u, int* __restrict__ flag) {
    __shared__ int cnt;
    if (threadIdx.x == 0) cnt = 0;
    __syncthreads();
    float v = b2f(emb_u[2 * threadIdx.x + 64]);
    float a = fabsf(v);
    if (a > 1e-4f && a < 16.f) atomicAdd(&cnt, 1);
    __syncthreads();
    if (threadIdx.x == 0) *flag = (cnt > 128) ? 1 : 0;
}

// ---- weight packing: gate-row permutation row' = 4*j + t (t: 0=i,1=f,2=g,3=o) ----
__global__ void k_packw(const void* __restrict__ src, u16* __restrict__ dst,
                        int Kin, int Kpad, int total, const int* __restrict__ flag) {
    int i = blockIdx.x * 256 + threadIdx.x;
    if (i >= total) return;
    int n = i / Kpad, k = i - n * Kpad;
    int d = n >> 9, r = n & 511, j = r >> 2, t = r & 3;
    size_t si = (size_t)((d << 9) + (t << 7) + j) * Kin + k;
    u16 v = 0;
    if (k < Kin) {
        if (*flag) v = ((const u16*)src)[si];
        else       v = f2b(((const float*)src)[si]);
    }
    dst[i] = v;
}

__global__ void k_packb(const void* __restrict__ src, float* __restrict__ dst,
                        const int* __restrict__ flag) {
    int i = blockIdx.x * 256 + threadIdx.x;
    if (i >= 1024) return;
    int d = i >> 9, r = i & 511, j = r >> 2, t = r & 3;
    size_t si = (d << 9) + (t << 7) + j;
    dst[i] = (*flag) ? b2f(((const u16*)src)[si]) : ((const float*)src)[si];
}

// ---- FUSED kernel: blocks [0,nlstm) = LSTM role (chunk k); blocks
// [nlstm, nlstm+1024) = GEMM role (chunk k+1 -> gx_out, r9 structure).
// LSTM role (r10): depth-2 gx prefetch into a 3-buffer LDS ring + counted
// s_waitcnt vmcnt(1) barrier (T4) -- the per-step vmcnt(0) drain of
// __syncthreads was where fused-mode memory contention landed (+19us).
// Store h0seq FIRST, sched_barrier, then DMA: newest vmem op = this step's
// DMA, so vmcnt(1) retires everything older (incl. the DMA needed next step)
// while the current DMA stays in flight across the barrier (2-step budget).
// Last two steps use vmcnt(0) (no newer op guards the tail when !IS_L0).
template<int KPAD, bool EMBED, bool IS_L0>
__global__ __launch_bounds__(1024) void k_fused(
    const int* __restrict__ tok, const void* __restrict__ Asrc,
    const u16* __restrict__ W, const float* __restrict__ bias,
    u16* __restrict__ gx_out, const u16* __restrict__ gx_in,
    const u16* __restrict__ Whp,
    u16* __restrict__ h0seq, float* __restrict__ hT,
    u16* __restrict__ hstate, float* __restrict__ cstate,
    int k, int nlstm, int soff0g, int soff1g, const int* __restrict__ flag)
{
    __shared__ __align__(16) char smem[SMEM_BYTES];
    const int tid = threadIdx.x;

    if ((int)blockIdx.x < nlstm) {
        // ================= LSTM role =================
        u16* hb = (u16*)smem;                    // [2][16][136]
        u16* gb = (u16*)(smem + 8704);           // [3][16][520] ring
        const int d    = blockIdx.x >> 4;
        const int bg   = blockIdx.x & 15;
        const int wv   = tid >> 6, lane = tid & 63, quad = lane >> 4, col = lane & 15;
        const int soff = (d == 0) ? CH * k : CH * (NCH - 1 - k);

        for (int i = tid; i < 2 * 16 * 136; i += 1024) hb[i] = 0;
        __syncthreads();                          // zero visible before state load
        if (k > 0) {
            for (int i = tid; i < 16 * 128; i += 1024) {
                int bl = i >> 7, j = i & 127;
                hb[bl * 136 + j] = hstate[((size_t)d * BATCH + bg * 16 + bl) * 128 + j];
            }
        }

        // A-frags of W_hh: A[m=lane&15][k=quad*8+j]  [m120-verified]
        const u16* Wd = Whp + (size_t)d * 512 * 128;
        bf16x8 wf[2][4];
#pragma unroll
        for (int mt = 0; mt < 2; ++mt)
#pragma unroll
            for (int ks = 0; ks < 4; ++ks)
                wf[mt][ks] = *(const bf16x8*)(Wd + (size_t)(((wv * 2 + mt) * 16) + col) * 128 + ks * 32 + quad * 8);

        const u16* gxd = gx_in + (size_t)d * GXC_DIR;
        auto sloc = [&](int si) { return (d == 0) ? si : (CH - 1 - si); };
        auto prefetch = [&](int si, int B) {      // DMA gx row of step si -> ring buf B
            const u16* g0 = gxd + ((size_t)sloc(si) * BATCH + bg * 16 + wv) * 512 + lane * 8;
            __builtin_amdgcn_global_load_lds((const __attribute__((address_space(1))) void*)g0,
                (__attribute__((address_space(3))) void*)(gb + (B * 16 + wv) * 520), 16, 0, 0);
        };
        auto n3 = [](int x) { x += 2; return (x >= 3) ? x - 3 : x; };   // (x+2)%3

        float c[2];
#pragma unroll
        for (int mt = 0; mt < 2; ++mt)
            c[mt] = (k > 0) ? cstate[((size_t)d * BATCH + bg * 16 + col) * 128 + (wv * 2 + mt) * 4 + quad] : 0.f;

        auto step = [&](int si, int P, int bCur) {
            // (1) store PREV step's h first (ack drains over the whole step)
            if constexpr (IS_L0) {
                if (si > 0) {
                    int sp = soff + ((d == 0) ? (si - 1) : (CH - si));
                    ushort2 hv = *(const ushort2*)(hb + (P * 16 + wv) * 136 + lane * 2);
                    *(ushort2*)(h0seq + ((size_t)sp * BATCH + bg * 16 + wv) * 256 + (d << 7) + lane * 2) = hv;
                }
            }
            __builtin_amdgcn_sched_barrier(0);    // pin store before DMA (newest = DMA)
            // (2) deep prefetch: step si+2 -> ring buf (bCur+2)%3
            if (si + 2 < CH) prefetch(si + 2, n3(bCur));
            __builtin_amdgcn_sched_barrier(0);
            // (3) compute from ring buf bCur / hbuf P
            bf16x8 hf[4];
#pragma unroll
            for (int ks = 0; ks < 4; ++ks)
                hf[ks] = *(const bf16x8*)(hb + (P * 16 + col) * 136 + ks * 32 + quad * 8);
            f32x4 z[2];
#pragma unroll
            for (int mt = 0; mt < 2; ++mt) {
                ushort4 gv = *(const ushort4*)(gb + (bCur * 16 + col) * 520 + (wv * 2 + mt) * 16 + quad * 4);
                z[mt][0] = b2f(gv.x); z[mt][1] = b2f(gv.y); z[mt][2] = b2f(gv.z); z[mt][3] = b2f(gv.w);
            }
#pragma unroll
            for (int ks = 0; ks < 4; ++ks)
#pragma unroll
                for (int mt = 0; mt < 2; ++mt)
                    z[mt] = __builtin_amdgcn_mfma_f32_16x16x32_bf16(wf[mt][ks], hf[ks], z[mt], 0, 0, 0);
#pragma unroll
            for (int mt = 0; mt < 2; ++mt) {
                float iv = sigf(z[mt][0]), fv = sigf(z[mt][1]);
                float gg = tanhf_fast(z[mt][2]), ov = sigf(z[mt][3]);
                c[mt] = fv * c[mt] + iv * gg;
                float hv = ov * tanhf_fast(c[mt]);
                const int j = (wv * 2 + mt) * 4 + quad;
                hb[((P ^ 1) * 16 + col) * 136 + j] = f2b(hv);
                if constexpr (!IS_L0) {
                    if (k == NCH - 1 && si == CH - 1)
                        hT[((size_t)d * BATCH + bg * 16 + col) * 128 + j] = hv;
                }
            }
            // (4) counted-vmcnt barrier (T4): current DMA stays in flight.
            if (si + 2 < CH)
                asm volatile("s_waitcnt vmcnt(1) lgkmcnt(0)\n\ts_barrier" ::: "memory");
            else
                asm volatile("s_waitcnt vmcnt(0) lgkmcnt(0)\n\ts_barrier" ::: "memory");
        };

        prefetch(0, 0);
        prefetch(1, 1);
        __syncthreads();                          // hbuf init + gx(steps 0,1) staged

        int b0i = 0, b1i = 1;                     // ring indices for even/odd steps
        for (int si = 0; si < CH; si += 2) {
            step(si,     0, b0i);
            step(si + 1, 1, b1i);
            b0i = n3(b0i); b1i = n3(b1i);
        }

        if constexpr (IS_L0) {                    // final step's h (in hbuf[0])
            int sp = soff + ((d == 0) ? (CH - 1) : 0);
            ushort2 hv = *(const ushort2*)(hb + wv * 136 + lane * 2);
            *(ushort2*)(h0seq + ((size_t)sp * BATCH + bg * 16 + wv) * 256 + (d << 7) + lane * 2) = hv;
        }
        if (k < NCH - 1) {                        // persist h/c for next chunk
            for (int i = tid; i < 16 * 128; i += 1024) {
                int bl = i >> 7, j = i & 127;
                hstate[((size_t)d * BATCH + bg * 16 + bl) * 128 + j] = hb[bl * 136 + j];
            }
#pragma unroll
            for (int mt = 0; mt < 2; ++mt)
                cstate[((size_t)d * BATCH + bg * 16 + col) * 128 + (wv * 2 + mt) * 4 + quad] = c[mt];
        }
        return;
    }

    // ========== GEMM role (r9): A-frags in VGPR, B dbuf, issue-early/write-late ==========
    const int g = (int)blockIdx.x - nlstm;        // 0..1023
    constexpr int KSTEPS = KPAD / 32;
    constexpr int AST    = KPAD + 8;              // u16 row stride (16B-aligned rows)
    constexpr int CPR    = KPAD / 8;              // uint4 chunks per row
    constexpr int NCHK   = 64 * CPR;              // uint4 chunks per 64xKPAD tile
    u16* As  = (u16*)smem;                         // [64][AST]
    u16* Bs0 = (u16*)(smem + (size_t)64 * AST * 2);
    u16* Bs1 = Bs0 + (size_t)64 * AST;
    const int dir  = g >> 9;
    const int m0   = (g & 511) * 64;               // within chunk rows (0..32767)
    const int soff = dir ? soff1g : soff0g;
    const size_t mg0 = (size_t)soff * BATCH;
    const int w = tid >> 6, lane = tid & 63, quad = lane >> 4, l16 = lane & 15;
    const int wm = w >> 2, wn = w & 3;             // 4m x 4n waves, 16x16 frag each
    const bool is_bf = EMBED ? (*flag != 0) : true;
    const u16* Wdir = W + (size_t)dir * 512 * KPAD;

    // ---- stage A once (gather + f2b happen ONCE) ----
    for (int ch = tid; ch < NCHK; ch += 1024) {
        int row = ch / CPR, seg = ch % CPR;
        uint4 v;
        if constexpr (EMBED) {
            u32 u[4];
            size_t m = mg0 + m0 + row;
            int s = (int)(m >> 8), b = (int)(m & 255);
            size_t aro = (size_t)tok[b * S_LEN + s] * EMB_D;
            if (is_bf) {
                const u16* ar = (const u16*)Asrc + aro;
#pragma unroll
                for (int i = 0; i < 4; ++i) {
                    int cc = seg * 8 + 2 * i;              // even -> 4B aligned pair
                    u[i] = (cc < EMB_D) ? *(const u32*)(ar + cc) : 0u;
                }
            } else {
                const float* ar = (const float*)Asrc + aro;
#pragma unroll
                for (int i = 0; i < 4; ++i) {
                    int cc = seg * 8 + 2 * i;
                    if (cc < EMB_D) {
                        float2 f = *(const float2*)(ar + cc);
                        u[i] = (u32)f2b(f.x) | ((u32)f2b(f.y) << 16);
                    } else u[i] = 0u;
                }
            }
            v.x = u[0]; v.y = u[1]; v.z = u[2]; v.w = u[3];
        } else {
            v = *(const uint4*)((const u16*)Asrc + (mg0 + m0 + row) * KPAD + seg * 8);
        }
        *(uint4*)(As + (size_t)row * AST + seg * 8) = v;
    }
    // ---- stage B(0) -> Bs0 ----
    for (int ch = tid; ch < NCHK; ch += 1024) {
        int row = ch / CPR, seg = ch % CPR;
        uint4 v = *(const uint4*)(Wdir + (size_t)row * KPAD + seg * 8);
        *(uint4*)(Bs0 + (size_t)row * AST + seg * 8) = v;
    }
    __syncthreads();                               // A + B0 visible

    // ---- cache A-frags in VGPRs (LDS read once, not 8x) ----
    bf16x8 afr[KSTEPS];
#pragma unroll
    for (int kk = 0; kk < KSTEPS; ++kk)
        afr[kk] = *(const bf16x8*)(As + (size_t)(wm * 16 + l16) * AST + kk * 32 + quad * 8);

    // ---- 8 n-subtiles: issue B(j+1) loads early, MFMA, write B(j+1), barrier ----
    for (int j = 0; j < 8; ++j) {
        uint4 v0, v1, v2;
        const bool more = (j + 1 < 8);
        if (more) {                                // issue-early (T14): L2-hot W loads
            const u16* Wj = Wdir + (size_t)(j + 1) * 64 * KPAD;
            { int row = tid / CPR, seg = tid % CPR;
              v0 = *(const uint4*)(Wj + (size_t)row * KPAD + seg * 8); }
            { int ch = tid + 1024; int row = ch / CPR, seg = ch % CPR;
              v1 = *(const uint4*)(Wj + (size_t)row * KPAD + seg * 8); }
            if (tid + 2048 < NCHK) { int ch = tid + 2048; int row = ch / CPR, seg = ch % CPR;
              v2 = *(const uint4*)(Wj + (size_t)row * KPAD + seg * 8); }
        }
        const u16* Bc = (j & 1) ? Bs1 : Bs0;
        f32x4 acc = {};
#pragma unroll
        for (int kk = 0; kk < KSTEPS; ++kk) {
            bf16x8 bf = *(const bf16x8*)(Bc + (size_t)(wn * 16 + l16) * AST + kk * 32 + quad * 8);
            acc = __builtin_amdgcn_mfma_f32_16x16x32_bf16(afr[kk], bf, acc, 0, 0, 0);
        }
        if (more) {                                // write-late into the other buffer
            u16* Bn = (j & 1) ? Bs0 : Bs1;
            { int row = tid / CPR, seg = tid % CPR;
              *(uint4*)(Bn + (size_t)row * AST + seg * 8) = v0; }
            { int ch = tid + 1024; int row = ch / CPR, seg = ch % CPR;
              *(uint4*)(Bn + (size_t)row * AST + seg * 8) = v1; }
            if (tid + 2048 < NCHK) { int ch = tid + 2048; int row = ch / CPR, seg = ch % CPR;
              *(uint4*)(Bn + (size_t)row * AST + seg * 8) = v2; }
        }
        __syncthreads();                           // publish B(j+1); guard dbuf reuse
        // C/D layout: col = lane&15, row = quad*4 + reg  [m89-verified]
#pragma unroll
        for (int r = 0; r < 4; ++r) {
            int mloc = m0 + wm * 16 + quad * 4 + r;
            int nloc = j * 64 + wn * 16 + l16;
            float vv = acc[r] + bias[dir * 512 + nloc];
            gx_out[(size_t)dir * GXC_DIR + (size_t)mloc * 512 + nloc] = f2b(vv);
        }
    }
}

// ---- FC head (dtype-flagged weights and output) ----
__global__ void k_fc(const float* __restrict__ hT,
                     const void* __restrict__ fc1w, const void* __restrict__ fc1b,
                     const void* __restrict__ fc2w, const void* __restrict__ fc2b,
                     void* __restrict__ out, const int* __restrict__ flag) {
    int b = blockIdx.x, j = threadIdx.x;
    bool is_bf = (*flag != 0);
    __shared__ float u[128];
    float a = is_bf ? b2f(((const u16*)fc1b)[j]) : ((const float*)fc1b)[j];
    for (int k = 0; k < 256; ++k) {
        float x = hT[((size_t)(k >> 7) * BATCH + b) * 128 + (k & 127)];
        float w = is_bf ? b2f(((const u16*)fc1w)[j * 256 + k]) : ((const float*)fc1w)[j * 256 + k];
        a += x * w;
    }
    u[j] = fmaxf(a, 0.f);
    __syncthreads();
    if (j < 2) {
        float a2 = is_bf ? b2f(((const u16*)fc2b)[j]) : ((const float*)fc2b)[j];
        for (int q = 0; q < 128; ++q) {
            float w = is_bf ? b2f(((const u16*)fc2w)[j * 128 + q]) : ((const float*)fc2w)[j * 128 + q];
            a2 += u[q] * w;
        }
        if (is_bf) ((u16*)out)[b * 2 + j] = f2b(a2);
        else       ((float*)out)[b * 2 + j] = a2;
    }
}

extern "C" void kernel_launch(void* const* d_in, const int* in_sizes, int n_in,
                              void* d_out, int out_size, void* d_ws, size_t ws_size,
                              hipStream_t stream) {
    const int*  tok   = (const int*)d_in[0];
    const void* emb   = d_in[1];
    const void* w_ih0 = d_in[2];
    const void* w_hh0 = d_in[3];
    const void* b0    = d_in[4];
    const void* w_ih1 = d_in[5];
    const void* w_hh1 = d_in[6];
    const void* b1    = d_in[7];
    const void* fc1w  = d_in[8];
    const void* fc1b  = d_in[9];
    const void* fc2w  = d_in[10];
    const void* fc2b  = d_in[11];

    char* ws = (char*)d_ws;
    size_t off = 0;
    auto alloc = [&](size_t bytes) -> void* {
        void* p = ws + off; off += (bytes + 255) & ~(size_t)255; return p;
    };
    int*   flag   = (int*)alloc(256);
    u16*   Wp0    = (u16*)alloc(1024 * 320 * 2);
    u16*   Wp1    = (u16*)alloc(1024 * 256 * 2);
    u16*   Whp0   = (u16*)alloc(1024 * 128 * 2);
    u16*   Whp1   = (u16*)alloc(1024 * 128 * 2);
    float* bp0    = (float*)alloc(1024 * 4);
    float* bp1    = (float*)alloc(1024 * 4);
    float* hT     = (float*)alloc((size_t)2 * BATCH * 128 * 4);
    u16*   hstate = (u16*)alloc((size_t)2 * BATCH * 128 * 2);
    float* cstate = (float*)alloc((size_t)2 * BATCH * 128 * 4);
    u16*   h0seq  = (u16*)alloc((size_t)SB * 256 * 2);           // 64 MiB
    size_t bufb   = 2 * GXC_DIR * sizeof(u16);                   // 64 MiB (both dirs)
    u16*   gxcA   = (u16*)alloc(bufb);
    bool overlap  = ws_size >= off + bufb;                       // room for 2nd buffer?
    u16*   gxcB   = overlap ? (u16*)alloc(bufb) : gxcA;

    k_detect<<<1, 256, 0, stream>>>((const u16*)emb, flag);

    k_packw<<<(1024 * 320 + 255) / 256, 256, 0, stream>>>(w_ih0, Wp0, 300, 320, 1024 * 320, flag);
    k_packw<<<(1024 * 256 + 255) / 256, 256, 0, stream>>>(w_ih1, Wp1, 256, 256, 1024 * 256, flag);
    k_packw<<<(1024 * 128 + 255) / 256, 256, 0, stream>>>(w_hh0, Whp0, 128, 128, 1024 * 128, flag);
    k_packw<<<(1024 * 128 + 255) / 256, 256, 0, stream>>>(w_hh1, Whp1, 128, 128, 1024 * 128, flag);
    k_packb<<<4, 256, 0, stream>>>(b0, bp0, flag);
    k_packb<<<4, 256, 0, stream>>>(b1, bp1, flag);

    const int NG = 1024;   // gemm blocks per chunk: 2 dirs x 512 m-tiles

    if (overlap) {
        // ---- L0: gemm chunk0 standalone, then lstm(k) || gemm(k+1) ----
        k_fused<320, true, true><<<NG, 1024, 0, stream>>>(
            tok, emb, Wp0, bp0, gxcA, gxcA, Whp0, h0seq, nullptr, hstate, cstate,
            0, 0, 0, CH * (NCH - 1), flag);
        for (int k = 0; k < NCH; ++k) {
            int ng = (k < NCH - 1) ? NG : 0;
            u16* gin  = (k & 1) ? gxcB : gxcA;
            u16* gout = (k & 1) ? gxcA : gxcB;
            k_fused<320, true, true><<<32 + ng, 1024, 0, stream>>>(
                tok, emb, Wp0, bp0, gout, gin, Whp0, h0seq, nullptr, hstate, cstate,
                k, 32, CH * (k + 1), CH * (NCH - 2 - k), flag);
        }
        // ---- L1 ----
        k_fused<256, false, false><<<NG, 1024, 0, stream>>>(
            nullptr, h0seq, Wp1, bp1, gxcA, gxcA, Whp1, nullptr, hT, hstate, cstate,
            0, 0, 0, CH * (NCH - 1), flag);
        for (int k = 0; k < NCH; ++k) {
            int ng = (k < NCH - 1) ? NG : 0;
            u16* gin  = (k & 1) ? gxcB : gxcA;
            u16* gout = (k & 1) ? gxcA : gxcB;
            k_fused<256, false, false><<<32 + ng, 1024, 0, stream>>>(
                nullptr, h0seq, Wp1, bp1, gout, gin, Whp1, nullptr, hT, hstate, cstate,
                k, 32, CH * (k + 1), CH * (NCH - 2 - k), flag);
        }
    } else {
        // ---- serial fallback (r6 schedule), single gxc buffer ----
        for (int k = 0; k < NCH; ++k) {
            k_fused<320, true, true><<<NG, 1024, 0, stream>>>(
                tok, emb, Wp0, bp0, gxcA, gxcA, Whp0, h0seq, nullptr, hstate, cstate,
                0, 0, CH * k, CH * (NCH - 1 - k), flag);
            k_fused<320, true, true><<<32, 1024, 0, stream>>>(
                tok, emb, Wp0, bp0, gxcA, gxcA, Whp0, h0seq, nullptr, hstate, cstate,
                k, 32, 0, 0, flag);
        }
        for (int k = 0; k < NCH; ++k) {
            k_fused<256, false, false><<<NG, 1024, 0, stream>>>(
                nullptr, h0seq, Wp1, bp1, gxcA, gxcA, Whp1, nullptr, hT, hstate, cstate,
                0, 0, CH * k, CH * (NCH - 1 - k), flag);
            k_fused<256, false, false><<<32, 1024, 0, stream>>>(
                nullptr, h0seq, Wp1, bp1, gxcA, gxcA, Whp1, nullptr, hT, hstate, cstate,
                k, 32, 0, 0, flag);
        }
    }
    k_fc<<<256, 128, 0, stream>>>(hT, fc1w, fc1b, fc2w, fc2b, d_out, flag);
}

// Round 11
// 1510.160 us; speedup vs baseline: 1.0380x; 1.0017x over previous
//
#include <hip/hip_runtime.h>

// Dims (fixed by the problem)
#define S_LEN 512
#define BATCH 256
#define EMB_D 300
#define EMB_PAD 320
#define HID 128
#define SB (S_LEN*BATCH)   // 131072 rows (time-major m = s*B + b)
#define CH 128             // time-chunk length
#define NCH 4              // number of chunks
#define GXC_DIR ((size_t)CH*BATCH*512)   // u16 per dir per buffer
#define SMEM_BYTES 125952  // 123 KiB: gemm A + 2xB tiles; >80K -> 1 block/CU (role isolation)

typedef __attribute__((ext_vector_type(8))) short bf16x8;   // 8 bf16 = 4 VGPRs
typedef __attribute__((ext_vector_type(4))) float f32x4;
typedef unsigned short u16;
typedef unsigned int   u32;

// ---- bf16 <-> f32 helpers ----
__device__ __forceinline__ float b2f(u16 u) {
    union { u32 i; float f; } v; v.i = ((u32)u) << 16; return v.f;
}
__device__ __forceinline__ u16 f2b(float f) {
    union { float f; u32 i; } v; v.f = f;
    u32 r = v.i + 0x7fffu + ((v.i >> 16) & 1u);   // round-to-nearest-even
    return (u16)(r >> 16);
}
__device__ __forceinline__ float sigf(float x) {
    return __builtin_amdgcn_rcpf(1.f + __expf(-x));
}
__device__ __forceinline__ float tanhf_fast(float x) {
    float e = __expf(2.f * x);
    return 1.f - 2.f * __builtin_amdgcn_rcpf(e + 1.f);
}

// ---- dtype detector: flag=1 if float tensors are bf16, 0 if f32 ----
__global__ void k_detect(const u16* __restrict__ emb_u, int* __restrict__ flag) {
    __shared__ int cnt;
    if (threadIdx.x == 0) cnt = 0;
    __syncthreads();
    float v = b2f(emb_u[2 * threadIdx.x + 64]);
    float a = fabsf(v);
    if (a > 1e-4f && a < 16.f) atomicAdd(&cnt, 1);
    __syncthreads();
    if (threadIdx.x == 0) *flag = (cnt > 128) ? 1 : 0;
}

// ---- weight packing: gate-row permutation row' = 4*j + t (t: 0=i,1=f,2=g,3=o) ----
__global__ void k_packw(const void* __restrict__ src, u16* __restrict__ dst,
                        int Kin, int Kpad, int total, const int* __restrict__ flag) {
    int i = blockIdx.x * 256 + threadIdx.x;
    if (i >= total) return;
    int n = i / Kpad, k = i - n * Kpad;
    int d = n >> 9, r = n & 511, j = r >> 2, t = r & 3;
    size_t si = (size_t)((d << 9) + (t << 7) + j) * Kin + k;
    u16 v = 0;
    if (k < Kin) {
        if (*flag) v = ((const u16*)src)[si];
        else       v = f2b(((const float*)src)[si]);
    }
    dst[i] = v;
}

__global__ void k_packb(const void* __restrict__ src, float* __restrict__ dst,
                        const int* __restrict__ flag) {
    int i = blockIdx.x * 256 + threadIdx.x;
    if (i >= 1024) return;
    int d = i >> 9, r = i & 511, j = r >> 2, t = r & 3;
    size_t si = (d << 9) + (t << 7) + j;
    dst[i] = (*flag) ? b2f(((const u16*)src)[si]) : ((const float*)src)[si];
}

// ---- FUSED kernel: blocks [0,nlstm) = LSTM role (chunk k); blocks
// [nlstm, nlstm+1024) = GEMM role (chunk k+1 -> gx_out, r9 structure).
// LSTM role (r11): depth-4 gx prefetch into a 6-buffer LDS ring. r10's
// occupancy integral showed gemm blocks live ~14us (all done by t~80) while
// the lstm role stretches 149.5 -> 169us under co-residency: the gemm's
// L2/L3/HBM traffic inflates the gx DMA latency past the old 2-step budget.
// Depth-4 gives ~4.7us of cover. Counted waits: ops newer than the needed
// DMA(si+1) = 3 DMAs + (IS_L0: 3 h0seq stores) -> vmcnt(6) L0 / vmcnt(3) L1;
// last 4 steps vmcnt(0).
template<int KPAD, bool EMBED, bool IS_L0>
__global__ __launch_bounds__(1024) void k_fused(
    const int* __restrict__ tok, const void* __restrict__ Asrc,
    const u16* __restrict__ W, const float* __restrict__ bias,
    u16* __restrict__ gx_out, const u16* __restrict__ gx_in,
    const u16* __restrict__ Whp,
    u16* __restrict__ h0seq, float* __restrict__ hT,
    u16* __restrict__ hstate, float* __restrict__ cstate,
    int k, int nlstm, int soff0g, int soff1g, const int* __restrict__ flag)
{
    __shared__ __align__(16) char smem[SMEM_BYTES];
    const int tid = threadIdx.x;

    if ((int)blockIdx.x < nlstm) {
        // ================= LSTM role =================
        u16* hb = (u16*)smem;                    // [2][16][136]
        u16* gb = (u16*)(smem + 8704);           // [6][16][520] ring (99840 B)
        const int d    = blockIdx.x >> 4;
        const int bg   = blockIdx.x & 15;
        const int wv   = tid >> 6, lane = tid & 63, quad = lane >> 4, col = lane & 15;
        const int soff = (d == 0) ? CH * k : CH * (NCH - 1 - k);

        for (int i = tid; i < 2 * 16 * 136; i += 1024) hb[i] = 0;
        __syncthreads();                          // zero visible before state load
        if (k > 0) {
            for (int i = tid; i < 16 * 128; i += 1024) {
                int bl = i >> 7, j = i & 127;
                hb[bl * 136 + j] = hstate[((size_t)d * BATCH + bg * 16 + bl) * 128 + j];
            }
        }

        // A-frags of W_hh: A[m=lane&15][k=quad*8+j]  [m120-verified]
        const u16* Wd = Whp + (size_t)d * 512 * 128;
        bf16x8 wf[2][4];
#pragma unroll
        for (int mt = 0; mt < 2; ++mt)
#pragma unroll
            for (int ks = 0; ks < 4; ++ks)
                wf[mt][ks] = *(const bf16x8*)(Wd + (size_t)(((wv * 2 + mt) * 16) + col) * 128 + ks * 32 + quad * 8);

        const u16* gxd = gx_in + (size_t)d * GXC_DIR;
        auto sloc = [&](int si) { return (d == 0) ? si : (CH - 1 - si); };
        auto prefetch = [&](int si, int B) {      // DMA gx row of step si -> ring buf B
            const u16* g0 = gxd + ((size_t)sloc(si) * BATCH + bg * 16 + wv) * 512 + lane * 8;
            __builtin_amdgcn_global_load_lds((const __attribute__((address_space(1))) void*)g0,
                (__attribute__((address_space(3))) void*)(gb + (B * 16 + wv) * 520), 16, 0, 0);
        };
        auto adv2 = [](int x) { x += 2; return (x >= 6) ? x - 6 : x; };   // (x+2)%6
        auto pl4  = [](int x) { x += 4; return (x >= 6) ? x - 6 : x; };   // (x+4)%6

        float c[2];
#pragma unroll
        for (int mt = 0; mt < 2; ++mt)
            c[mt] = (k > 0) ? cstate[((size_t)d * BATCH + bg * 16 + col) * 128 + (wv * 2 + mt) * 4 + quad] : 0.f;

        auto step = [&](int si, int P, int bCur) {
            // (1) store PREV step's h first (ack drains over following steps)
            if constexpr (IS_L0) {
                if (si > 0) {
                    int sp = soff + ((d == 0) ? (si - 1) : (CH - si));
                    ushort2 hv = *(const ushort2*)(hb + (P * 16 + wv) * 136 + lane * 2);
                    *(ushort2*)(h0seq + ((size_t)sp * BATCH + bg * 16 + wv) * 256 + (d << 7) + lane * 2) = hv;
                }
            }
            __builtin_amdgcn_sched_barrier(0);    // pin store before DMA
            // (2) depth-4 prefetch: step si+4 -> ring buf (bCur+4)%6
            if (si + 4 < CH) prefetch(si + 4, pl4(bCur));
            __builtin_amdgcn_sched_barrier(0);
            // (3) compute from ring buf bCur / hbuf P
            bf16x8 hf[4];
#pragma unroll
            for (int ks = 0; ks < 4; ++ks)
                hf[ks] = *(const bf16x8*)(hb + (P * 16 + col) * 136 + ks * 32 + quad * 8);
            f32x4 z[2];
#pragma unroll
            for (int mt = 0; mt < 2; ++mt) {
                ushort4 gv = *(const ushort4*)(gb + (bCur * 16 + col) * 520 + (wv * 2 + mt) * 16 + quad * 4);
                z[mt][0] = b2f(gv.x); z[mt][1] = b2f(gv.y); z[mt][2] = b2f(gv.z); z[mt][3] = b2f(gv.w);
            }
#pragma unroll
            for (int ks = 0; ks < 4; ++ks)
#pragma unroll
                for (int mt = 0; mt < 2; ++mt)
                    z[mt] = __builtin_amdgcn_mfma_f32_16x16x32_bf16(wf[mt][ks], hf[ks], z[mt], 0, 0, 0);
#pragma unroll
            for (int mt = 0; mt < 2; ++mt) {
                float iv = sigf(z[mt][0]), fv = sigf(z[mt][1]);
                float gg = tanhf_fast(z[mt][2]), ov = sigf(z[mt][3]);
                c[mt] = fv * c[mt] + iv * gg;
                float hv = ov * tanhf_fast(c[mt]);
                const int j = (wv * 2 + mt) * 4 + quad;
                hb[((P ^ 1) * 16 + col) * 136 + j] = f2b(hv);
                if constexpr (!IS_L0) {
                    if (k == NCH - 1 && si == CH - 1)
                        hT[((size_t)d * BATCH + bg * 16 + col) * 128 + j] = hv;
                }
            }
            // (4) counted-vmcnt barrier: the needed DMA(si+1) has exactly
            // 3 DMAs (+3 stores if IS_L0) newer than it -> <=6 / <=3
            // outstanding guarantees it retired; deeper DMAs stay in flight.
            if (si < CH - 4) {
                if constexpr (IS_L0)
                    asm volatile("s_waitcnt vmcnt(6) lgkmcnt(0)\n\ts_barrier" ::: "memory");
                else
                    asm volatile("s_waitcnt vmcnt(3) lgkmcnt(0)\n\ts_barrier" ::: "memory");
            } else {
                asm volatile("s_waitcnt vmcnt(0) lgkmcnt(0)\n\ts_barrier" ::: "memory");
            }
        };

        prefetch(0, 0);
        prefetch(1, 1);
        prefetch(2, 2);
        prefetch(3, 3);
        __syncthreads();                          // hbuf init + gx(steps 0-3) staged

        int b0i = 0, b1i = 1;                     // ring indices for even/odd steps
        for (int si = 0; si < CH; si += 2) {
            step(si,     0, b0i);
            step(si + 1, 1, b1i);
            b0i = adv2(b0i); b1i = adv2(b1i);
        }

        if constexpr (IS_L0) {                    // final step's h (in hbuf[0])
            int sp = soff + ((d == 0) ? (CH - 1) : 0);
            ushort2 hv = *(const ushort2*)(hb + wv * 136 + lane * 2);
            *(ushort2*)(h0seq + ((size_t)sp * BATCH + bg * 16 + wv) * 256 + (d << 7) + lane * 2) = hv;
        }
        if (k < NCH - 1) {                        // persist h/c for next chunk
            for (int i = tid; i < 16 * 128; i += 1024) {
                int bl = i >> 7, j = i & 127;
                hstate[((size_t)d * BATCH + bg * 16 + bl) * 128 + j] = hb[bl * 136 + j];
            }
#pragma unroll
            for (int mt = 0; mt < 2; ++mt)
                cstate[((size_t)d * BATCH + bg * 16 + col) * 128 + (wv * 2 + mt) * 4 + quad] = c[mt];
        }
        return;
    }

    // ========== GEMM role (r9): A-frags in VGPR, B dbuf, issue-early/write-late ==========
    const int g = (int)blockIdx.x - nlstm;        // 0..1023
    constexpr int KSTEPS = KPAD / 32;
    constexpr int AST    = KPAD + 8;              // u16 row stride (16B-aligned rows)
    constexpr int CPR    = KPAD / 8;              // uint4 chunks per row
    constexpr int NCHK   = 64 * CPR;              // uint4 chunks per 64xKPAD tile
    u16* As  = (u16*)smem;                         // [64][AST]
    u16* Bs0 = (u16*)(smem + (size_t)64 * AST * 2);
    u16* Bs1 = Bs0 + (size_t)64 * AST;
    const int dir  = g >> 9;
    const int m0   = (g & 511) * 64;               // within chunk rows (0..32767)
    const int soff = dir ? soff1g : soff0g;
    const size_t mg0 = (size_t)soff * BATCH;
    const int w = tid >> 6, lane = tid & 63, quad = lane >> 4, l16 = lane & 15;
    const int wm = w >> 2, wn = w & 3;             // 4m x 4n waves, 16x16 frag each
    const bool is_bf = EMBED ? (*flag != 0) : true;
    const u16* Wdir = W + (size_t)dir * 512 * KPAD;

    // ---- stage A once (gather + f2b happen ONCE) ----
    for (int ch = tid; ch < NCHK; ch += 1024) {
        int row = ch / CPR, seg = ch % CPR;
        uint4 v;
        if constexpr (EMBED) {
            u32 u[4];
            size_t m = mg0 + m0 + row;
            int s = (int)(m >> 8), b = (int)(m & 255);
            size_t aro = (size_t)tok[b * S_LEN + s] * EMB_D;
            if (is_bf) {
                const u16* ar = (const u16*)Asrc + aro;
#pragma unroll
                for (int i = 0; i < 4; ++i) {
                    int cc = seg * 8 + 2 * i;              // even -> 4B aligned pair
                    u[i] = (cc < EMB_D) ? *(const u32*)(ar + cc) : 0u;
                }
            } else {
                const float* ar = (const float*)Asrc + aro;
#pragma unroll
                for (int i = 0; i < 4; ++i) {
                    int cc = seg * 8 + 2 * i;
                    if (cc < EMB_D) {
                        float2 f = *(const float2*)(ar + cc);
                        u[i] = (u32)f2b(f.x) | ((u32)f2b(f.y) << 16);
                    } else u[i] = 0u;
                }
            }
            v.x = u[0]; v.y = u[1]; v.z = u[2]; v.w = u[3];
        } else {
            v = *(const uint4*)((const u16*)Asrc + (mg0 + m0 + row) * KPAD + seg * 8);
        }
        *(uint4*)(As + (size_t)row * AST + seg * 8) = v;
    }
    // ---- stage B(0) -> Bs0 ----
    for (int ch = tid; ch < NCHK; ch += 1024) {
        int row = ch / CPR, seg = ch % CPR;
        uint4 v = *(const uint4*)(Wdir + (size_t)row * KPAD + seg * 8);
        *(uint4*)(Bs0 + (size_t)row * AST + seg * 8) = v;
    }
    __syncthreads();                               // A + B0 visible

    // ---- cache A-frags in VGPRs (LDS read once, not 8x) ----
    bf16x8 afr[KSTEPS];
#pragma unroll
    for (int kk = 0; kk < KSTEPS; ++kk)
        afr[kk] = *(const bf16x8*)(As + (size_t)(wm * 16 + l16) * AST + kk * 32 + quad * 8);

    // ---- 8 n-subtiles: issue B(j+1) loads early, MFMA, write B(j+1), barrier ----
    for (int j = 0; j < 8; ++j) {
        uint4 v0, v1, v2;
        const bool more = (j + 1 < 8);
        if (more) {                                // issue-early (T14): L2-hot W loads
            const u16* Wj = Wdir + (size_t)(j + 1) * 64 * KPAD;
            { int row = tid / CPR, seg = tid % CPR;
              v0 = *(const uint4*)(Wj + (size_t)row * KPAD + seg * 8); }
            { int ch = tid + 1024; int row = ch / CPR, seg = ch % CPR;
              v1 = *(const uint4*)(Wj + (size_t)row * KPAD + seg * 8); }
            if (tid + 2048 < NCHK) { int ch = tid + 2048; int row = ch / CPR, seg = ch % CPR;
              v2 = *(const uint4*)(Wj + (size_t)row * KPAD + seg * 8); }
        }
        const u16* Bc = (j & 1) ? Bs1 : Bs0;
        f32x4 acc = {};
#pragma unroll
        for (int kk = 0; kk < KSTEPS; ++kk) {
            bf16x8 bf = *(const bf16x8*)(Bc + (size_t)(wn * 16 + l16) * AST + kk * 32 + quad * 8);
            acc = __builtin_amdgcn_mfma_f32_16x16x32_bf16(afr[kk], bf, acc, 0, 0, 0);
        }
        if (more) {                                // write-late into the other buffer
            u16* Bn = (j & 1) ? Bs0 : Bs1;
            { int row = tid / CPR, seg = tid % CPR;
              *(uint4*)(Bn + (size_t)row * AST + seg * 8) = v0; }
            { int ch = tid + 1024; int row = ch / CPR, seg = ch % CPR;
              *(uint4*)(Bn + (size_t)row * AST + seg * 8) = v1; }
            if (tid + 2048 < NCHK) { int ch = tid + 2048; int row = ch / CPR, seg = ch % CPR;
              *(uint4*)(Bn + (size_t)row * AST + seg * 8) = v2; }
        }
        __syncthreads();                           // publish B(j+1); guard dbuf reuse
        // C/D layout: col = lane&15, row = quad*4 + reg  [m89-verified]
#pragma unroll
        for (int r = 0; r < 4; ++r) {
            int mloc = m0 + wm * 16 + quad * 4 + r;
            int nloc = j * 64 + wn * 16 + l16;
            float vv = acc[r] + bias[dir * 512 + nloc];
            gx_out[(size_t)dir * GXC_DIR + (size_t)mloc * 512 + nloc] = f2b(vv);
        }
    }
}

// ---- FC head (dtype-flagged weights and output) ----
__global__ void k_fc(const float* __restrict__ hT,
                     const void* __restrict__ fc1w, const void* __restrict__ fc1b,
                     const void* __restrict__ fc2w, const void* __restrict__ fc2b,
                     void* __restrict__ out, const int* __restrict__ flag) {
    int b = blockIdx.x, j = threadIdx.x;
    bool is_bf = (*flag != 0);
    __shared__ float u[128];
    float a = is_bf ? b2f(((const u16*)fc1b)[j]) : ((const float*)fc1b)[j];
    for (int k = 0; k < 256; ++k) {
        float x = hT[((size_t)(k >> 7) * BATCH + b) * 128 + (k & 127)];
        float w = is_bf ? b2f(((const u16*)fc1w)[j * 256 + k]) : ((const float*)fc1w)[j * 256 + k];
        a += x * w;
    }
    u[j] = fmaxf(a, 0.f);
    __syncthreads();
    if (j < 2) {
        float a2 = is_bf ? b2f(((const u16*)fc2b)[j]) : ((const float*)fc2b)[j];
        for (int q = 0; q < 128; ++q) {
            float w = is_bf ? b2f(((const u16*)fc2w)[j * 128 + q]) : ((const float*)fc2w)[j * 128 + q];
            a2 += u[q] * w;
        }
        if (is_bf) ((u16*)out)[b * 2 + j] = f2b(a2);
        else       ((float*)out)[b * 2 + j] = a2;
    }
}

extern "C" void kernel_launch(void* const* d_in, const int* in_sizes, int n_in,
                              void* d_out, int out_size, void* d_ws, size_t ws_size,
                              hipStream_t stream) {
    const int*  tok   = (const int*)d_in[0];
    const void* emb   = d_in[1];
    const void* w_ih0 = d_in[2];
    const void* w_hh0 = d_in[3];
    const void* b0    = d_in[4];
    const void* w_ih1 = d_in[5];
    const void* w_hh1 = d_in[6];
    const void* b1    = d_in[7];
    const void* fc1w  = d_in[8];
    const void* fc1b  = d_in[9];
    const void* fc2w  = d_in[10];
    const void* fc2b  = d_in[11];

    char* ws = (char*)d_ws;
    size_t off = 0;
    auto alloc = [&](size_t bytes) -> void* {
        void* p = ws + off; off += (bytes + 255) & ~(size_t)255; return p;
    };
    int*   flag   = (int*)alloc(256);
    u16*   Wp0    = (u16*)alloc(1024 * 320 * 2);
    u16*   Wp1    = (u16*)alloc(1024 * 256 * 2);
    u16*   Whp0   = (u16*)alloc(1024 * 128 * 2);
    u16*   Whp1   = (u16*)alloc(1024 * 128 * 2);
    float* bp0    = (float*)alloc(1024 * 4);
    float* bp1    = (float*)alloc(1024 * 4);
    float* hT     = (float*)alloc((size_t)2 * BATCH * 128 * 4);
    u16*   hstate = (u16*)alloc((size_t)2 * BATCH * 128 * 2);
    float* cstate = (float*)alloc((size_t)2 * BATCH * 128 * 4);
    u16*   h0seq  = (u16*)alloc((size_t)SB * 256 * 2);           // 64 MiB
    size_t bufb   = 2 * GXC_DIR * sizeof(u16);                   // 64 MiB (both dirs)
    u16*   gxcA   = (u16*)alloc(bufb);
    bool overlap  = ws_size >= off + bufb;                       // room for 2nd buffer?
    u16*   gxcB   = overlap ? (u16*)alloc(bufb) : gxcA;

    k_detect<<<1, 256, 0, stream>>>((const u16*)emb, flag);

    k_packw<<<(1024 * 320 + 255) / 256, 256, 0, stream>>>(w_ih0, Wp0, 300, 320, 1024 * 320, flag);
    k_packw<<<(1024 * 256 + 255) / 256, 256, 0, stream>>>(w_ih1, Wp1, 256, 256, 1024 * 256, flag);
    k_packw<<<(1024 * 128 + 255) / 256, 256, 0, stream>>>(w_hh0, Whp0, 128, 128, 1024 * 128, flag);
    k_packw<<<(1024 * 128 + 255) / 256, 256, 0, stream>>>(w_hh1, Whp1, 128, 128, 1024 * 128, flag);
    k_packb<<<4, 256, 0, stream>>>(b0, bp0, flag);
    k_packb<<<4, 256, 0, stream>>>(b1, bp1, flag);

    const int NG = 1024;   // gemm blocks per chunk: 2 dirs x 512 m-tiles

    if (overlap) {
        // ---- L0: gemm chunk0 standalone, then lstm(k) || gemm(k+1) ----
        k_fused<320, true, true><<<NG, 1024, 0, stream>>>(
            tok, emb, Wp0, bp0, gxcA, gxcA, Whp0, h0seq, nullptr, hstate, cstate,
            0, 0, 0, CH * (NCH - 1), flag);
        for (int k = 0; k < NCH; ++k) {
            int ng = (k < NCH - 1) ? NG : 0;
            u16* gin  = (k & 1) ? gxcB : gxcA;
            u16* gout = (k & 1) ? gxcA : gxcB;
            k_fused<320, true, true><<<32 + ng, 1024, 0, stream>>>(
                tok, emb, Wp0, bp0, gout, gin, Whp0, h0seq, nullptr, hstate, cstate,
                k, 32, CH * (k + 1), CH * (NCH - 2 - k), flag);
        }
        // ---- L1 ----
        k_fused<256, false, false><<<NG, 1024, 0, stream>>>(
            nullptr, h0seq, Wp1, bp1, gxcA, gxcA, Whp1, nullptr, hT, hstate, cstate,
            0, 0, 0, CH * (NCH - 1), flag);
        for (int k = 0; k < NCH; ++k) {
            int ng = (k < NCH - 1) ? NG : 0;
            u16* gin  = (k & 1) ? gxcB : gxcA;
            u16* gout = (k & 1) ? gxcA : gxcB;
            k_fused<256, false, false><<<32 + ng, 1024, 0, stream>>>(
                nullptr, h0seq, Wp1, bp1, gout, gin, Whp1, nullptr, hT, hstate, cstate,
                k, 32, CH * (k + 1), CH * (NCH - 2 - k), flag);
        }
    } else {
        // ---- serial fallback (r6 schedule), single gxc buffer ----
        for (int k = 0; k < NCH; ++k) {
            k_fused<320, true, true><<<NG, 1024, 0, stream>>>(
                tok, emb, Wp0, bp0, gxcA, gxcA, Whp0, h0seq, nullptr, hstate, cstate,
                0, 0, CH * k, CH * (NCH - 1 - k), flag);
            k_fused<320, true, true><<<32, 1024, 0, stream>>>(
                tok, emb, Wp0, bp0, gxcA, gxcA, Whp0, h0seq, nullptr, hstate, cstate,
                k, 32, 0, 0, flag);
        }
        for (int k = 0; k < NCH; ++k) {
            k_fused<256, false, false><<<NG, 1024, 0, stream>>>(
                nullptr, h0seq, Wp1, bp1, gxcA, gxcA, Whp1, nullptr, hT, hstate, cstate,
                0, 0, CH * k, CH * (NCH - 1 - k), flag);
            k_fused<256, false, false><<<32, 1024, 0, stream>>>(
                nullptr, h0seq, Wp1, bp1, gxcA, gxcA, Whp1, nullptr, hT, hstate, cstate,
                k, 32, 0, 0, flag);
        }
    }
    k_fc<<<256, 128, 0, stream>>>(hT, fc1w, fc1b, fc2w, fc2b, d_out, flag);
}